// Round 16
// baseline (2800.863 us; speedup 1.0000x reference)
//
#include <hip/hip_runtime.h>
#include <math.h>

#define NB 64
#define NT 512
#define ND 512
#define NH 256
#define NG 1024   // 4*H
#define NK 32
#define NBT (NB*NT)

__device__ __forceinline__ float sigf(float x) { return 1.f / (1.f + expf(-x)); }
__device__ __forceinline__ float hsum4(float4 v) { return v.x + v.y + v.z + v.w; }

// ---------------------------------------------------------------------------
// Weight prep (round-8 layout):
// ww[(((dir*4+s)*32 + g*8+j)*512 + tid)*4 + e] = Whh_dir[g*256+s*64+u][part*32+j*4+e]
// ---------------------------------------------------------------------------
__global__ void k_wprep3(const float* __restrict__ Wf, const float* __restrict__ Wb,
                         float* __restrict__ ww) {
    int f = blockIdx.x * 256 + threadIdx.x;      // 0 .. 524287
    int e   = f & 3;
    int tid = (f >> 2) & 511;
    int gj  = (f >> 11) & 31;
    int s   = (f >> 16) & 3;
    int dir = (f >> 18) & 1;
    int u = tid & 63, part = tid >> 6;
    int g = gj >> 3, j = gj & 7;
    const float* W = dir ? Wb : Wf;
    int row = g * 256 + s * 64 + u;
    int col = part * 32 + j * 4 + e;
    ww[f] = W[row * 256 + col];
}

// ---------------------------------------------------------------------------
// Input projection GEMM v4: round-12 k_gemm2 body (BK=32, register-prefetch
// pipeline — validated correct in r12) with __launch_bounds__(256, 2):
// 2 waves/EU -> 256-VGPR budget, so the ~32 prefetch regs + acc[8][8] fit
// without spilling (r12's spill was the (256,4) bound's 64-reg cap).
// Ascending-k summation: bit-identical logits.
// ---------------------------------------------------------------------------
__global__ __launch_bounds__(256, 2)
void k_gemm4(const float* __restrict__ x, const float* __restrict__ Wf,
             const float* __restrict__ Wb, const float* __restrict__ bf,
             const float* __restrict__ bb, float* __restrict__ xpF,
             float* __restrict__ xpB, int bxBase) {
    __shared__ float As[32][132];
    __shared__ float Bs[32][132];
    int tid = threadIdx.x;
    int bx = blockIdx.x + bxBase;
    int dir = bx >> 3;
    const float* W    = dir ? Wb : Wf;
    const float* bias = dir ? bb : bf;
    float* xp         = dir ? xpB : xpF;
    int r0 = blockIdx.y << 7;
    int g0 = (bx & 7) << 7;
    int rl = tid >> 1, kq = (tid & 1) << 4;      // row 0..127, K-offset 0/16
    const float* xa = x + (size_t)(r0 + rl) * ND + kq;
    const float* wa = W + (size_t)(g0 + rl) * ND + kq;
    int tx = tid & 15, ty = tid >> 4;

    float4 pa0, pa1, pa2, pa3, pb0, pb1, pb2, pb3;
    pa0 = *(const float4*)(xa + 0);  pa1 = *(const float4*)(xa + 4);
    pa2 = *(const float4*)(xa + 8);  pa3 = *(const float4*)(xa + 12);
    pb0 = *(const float4*)(wa + 0);  pb1 = *(const float4*)(wa + 4);
    pb2 = *(const float4*)(wa + 8);  pb3 = *(const float4*)(wa + 12);

    float acc[8][8] = {};
    for (int kt = 0; kt < ND; kt += 32) {
        As[kq+ 0][rl]=pa0.x; As[kq+ 1][rl]=pa0.y; As[kq+ 2][rl]=pa0.z; As[kq+ 3][rl]=pa0.w;
        As[kq+ 4][rl]=pa1.x; As[kq+ 5][rl]=pa1.y; As[kq+ 6][rl]=pa1.z; As[kq+ 7][rl]=pa1.w;
        As[kq+ 8][rl]=pa2.x; As[kq+ 9][rl]=pa2.y; As[kq+10][rl]=pa2.z; As[kq+11][rl]=pa2.w;
        As[kq+12][rl]=pa3.x; As[kq+13][rl]=pa3.y; As[kq+14][rl]=pa3.z; As[kq+15][rl]=pa3.w;
        Bs[kq+ 0][rl]=pb0.x; Bs[kq+ 1][rl]=pb0.y; Bs[kq+ 2][rl]=pb0.z; Bs[kq+ 3][rl]=pb0.w;
        Bs[kq+ 4][rl]=pb1.x; Bs[kq+ 5][rl]=pb1.y; Bs[kq+ 6][rl]=pb1.z; Bs[kq+ 7][rl]=pb1.w;
        Bs[kq+ 8][rl]=pb2.x; Bs[kq+ 9][rl]=pb2.y; Bs[kq+10][rl]=pb2.z; Bs[kq+11][rl]=pb2.w;
        Bs[kq+12][rl]=pb3.x; Bs[kq+13][rl]=pb3.y; Bs[kq+14][rl]=pb3.z; Bs[kq+15][rl]=pb3.w;
        __syncthreads();
        if (kt + 32 < ND) {   // issue next chunk's loads; overlap with compute
            const float* xn = xa + kt + 32;
            const float* wn = wa + kt + 32;
            pa0 = *(const float4*)(xn + 0);  pa1 = *(const float4*)(xn + 4);
            pa2 = *(const float4*)(xn + 8);  pa3 = *(const float4*)(xn + 12);
            pb0 = *(const float4*)(wn + 0);  pb1 = *(const float4*)(wn + 4);
            pb2 = *(const float4*)(wn + 8);  pb3 = *(const float4*)(wn + 12);
        }
        #pragma unroll
        for (int kk = 0; kk < 32; ++kk) {
            float4 av0 = *(const float4*)(&As[kk][ty << 3]);
            float4 av1 = *(const float4*)(&As[kk][(ty << 3) + 4]);
            float4 bv0 = *(const float4*)(&Bs[kk][tx << 3]);
            float4 bv1 = *(const float4*)(&Bs[kk][(tx << 3) + 4]);
            float aa[8] = {av0.x, av0.y, av0.z, av0.w, av1.x, av1.y, av1.z, av1.w};
            float bbv[8] = {bv0.x, bv0.y, bv0.z, bv0.w, bv1.x, bv1.y, bv1.z, bv1.w};
            #pragma unroll
            for (int i = 0; i < 8; ++i)
                #pragma unroll
                for (int j = 0; j < 8; ++j)
                    acc[i][j] += aa[i] * bbv[j];
        }
        __syncthreads();
    }
    float bv[8];
    #pragma unroll
    for (int j = 0; j < 8; ++j) bv[j] = bias[g0 + (tx << 3) + j];
    #pragma unroll
    for (int i = 0; i < 8; ++i) {
        float* orow = xp + (size_t)(r0 + (ty << 3) + i) * NG + g0 + (tx << 3);
        float4 o0 = {acc[i][0]+bv[0], acc[i][1]+bv[1], acc[i][2]+bv[2], acc[i][3]+bv[3]};
        float4 o1 = {acc[i][4]+bv[4], acc[i][5]+bv[5], acc[i][6]+bv[6], acc[i][7]+bv[7]};
        *(float4*)orow = o0;
        *(float4*)(orow + 4) = o1;
    }
}

// ---------------------------------------------------------------------------
// lstm macros (round-8)
// ---------------------------------------------------------------------------
#define FMA4(A, W, H) { (A).x += (W).x*(H).x; (A).y += (W).y*(H).y; \
                        (A).z += (W).z*(H).z; (A).w += (W).w*(H).w; }

#define DECLR(g) \
    float4 wr##g##_0 = wwp[qb + ((g)*8+0)*512]; \
    float4 wr##g##_1 = wwp[qb + ((g)*8+1)*512]; \
    float4 wr##g##_2 = wwp[qb + ((g)*8+2)*512]; \
    float4 wr##g##_3 = wwp[qb + ((g)*8+3)*512]; \
    float4 wr##g##_4 = wwp[qb + ((g)*8+4)*512];

#define DOTRJ(j) { float4 h_ = *(const float4*)(hb + (j)*4); \
    FMA4(a0, wr0_##j, h_) FMA4(a1, wr1_##j, h_) \
    FMA4(a2, wr2_##j, h_) FMA4(a3, wr3_##j, h_) }

#define DOTLJ(jj, j) { float4 h_ = *(const float4*)(hb + (j)*4); \
    { float4 l_ = lds_w[(0*3+(jj))*512 + tid]; FMA4(a0, l_, h_) } \
    { float4 l_ = lds_w[(1*3+(jj))*512 + tid]; FMA4(a1, l_, h_) } \
    { float4 l_ = lds_w[(2*3+(jj))*512 + tid]; FMA4(a2, l_, h_) } \
    { float4 l_ = lds_w[(3*3+(jj))*512 + tid]; FMA4(a3, l_, h_) } }

#define DOTALL DOTRJ(0) DOTRJ(1) DOTRJ(2) DOTRJ(3) DOTRJ(4) \
               DOTLJ(0,5) DOTLJ(1,6) DOTLJ(2,7)

// ---------------------------------------------------------------------------
// LSTM recurrence — round-15 k_lstm4b VERBATIM (best measured: 1650 us).
// ---------------------------------------------------------------------------
__global__ void
__attribute__((amdgpu_flat_work_group_size(512, 512)))
k_lstm4b(const float* __restrict__ xpF, const float* __restrict__ xpB,
         const float* __restrict__ ww, const int* __restrict__ lengths,
         float* hsF, float* hsB, int hstr, int* flags, int gBase) {
    int bi = blockIdx.x;
    int g   = (bi & 7) + 8 * (bi >> 5) + gBase;  // 0..63: dir*32 + group
    int s   = (bi >> 3) & 3;                     // u-slice; siblings share bi&7
    int dir = g >> 5;
    int b0  = (g & 31) * 2;
    const float* xp = dir ? xpB : xpF;
    float* hsD      = dir ? hsB : hsF;

    int tid = threadIdx.x;
    int u  = tid & 63;
    int wv = tid >> 6;                           // wave = v-chunk (part) 0..7

    __shared__ float4 lds_w[12 * 512];           // 96 KB
    __shared__ __align__(16) float hfull[2][256];
    __shared__ float4 lds_part[2][8][64];        // 16 KB
    __shared__ int len4[2];

    const float4* wwp = (const float4*)ww;
    int qb = ((dir * 4 + s) * 32) * 512 + tid;

    DECLR(0) DECLR(1) DECLR(2) DECLR(3)          // 20 named quads -> VGPRs
    #pragma unroll
    for (int gg = 0; gg < 4; ++gg)
        #pragma unroll
        for (int jj = 0; jj < 3; ++jj)
            lds_w[(gg * 3 + jj) * 512 + tid] = wwp[qb + (gg * 8 + 5 + jj) * 512];

    if (tid < 2) len4[tid] = lengths[b0 + tid];
    ((float*)hfull)[tid] = 0.f;                  // 512 floats exactly
    float c_state = 0.f;
    __syncthreads();

    // staging assignment (threads 0..191): 96 ulongs per batch
    int sb   = (tid < 192) ? (tid / 96) : 0;     // batch 0..1
    int sr   = tid - sb * 96;
    int spsi = (sr >> 5) & 3, sq = sr & 31;
    int ssl  = spsi + (spsi >= s);               // partner slice
    unsigned long long* sdst =
        (unsigned long long*)&hfull[sb & 1][ssl * 64 + sq * 2];
    const float* ssrc0 = hsD + (size_t)(b0 + (sb & 1)) * NT * hstr + ssl * 64 + sq * 2;

    // poller assignment (threads 0..7): (pb, ps)
    int pb = tid & 1, ps = (tid >> 1) & 3;
    const int* pollp = flags + ((((dir << 6) + b0 + pb) << 2) + ps) * 512;

    // update-wave global h pointer (waves 0..1)
    float* hwp = hsD + (size_t)(b0 + (wv & 1)) * NT * hstr + (s << 6) + u;
    // release flag pointer (wave 0 lanes 0..1: u = batch)
    int* flrelW0 = flags + ((((dir << 6) + b0 + (u & 1)) << 2) + s) * 512;

    for (int tt = 0; tt < NT; ++tt) {
        int t = dir ? (NT - 1 - tt) : tt;

        // A: xp prefetch (waves 0..1, batch wv's 4 gate columns)
        float x0 = 0.f, x1 = 0.f, x2 = 0.f, x3 = 0.f;
        if (wv < 2) {
            const float* xr = xp + ((size_t)(b0 + wv) * NT + t) * NG + (s << 6) + u;
            x0 = xr[0]; x1 = xr[256]; x2 = xr[512]; x3 = xr[768];
        }
        // B: poll partner flags RELAXED
        if (tt > 0 && tid < 8 && ps != s && t < len4[pb]) {
            const int* fp = pollp + (tt - 1);
            while (__hip_atomic_load(fp, __ATOMIC_RELAXED,
                                     __HIP_MEMORY_SCOPE_AGENT) == 0) {}
        }
        __syncthreads();   // C: flag loads complete block-wide

        // D: stage partner h via 64-bit relaxed atomic loads
        if (tt > 0 && tid < 192 && t < len4[sb]) {
            int t_prev = dir ? (t + 1) : (t - 1);
            unsigned long long v = __hip_atomic_load(
                (const unsigned long long*)(ssrc0 + (size_t)t_prev * hstr),
                __ATOMIC_RELAXED, __HIP_MEMORY_SCOPE_AGENT);
            *sdst = v;
        }
        __syncthreads();   // E

        // F: 2 dots (block-uniform skip per batch)
        #pragma unroll
        for (int b = 0; b < 2; ++b) {
            if (tt > 0 && t < len4[b]) {
                const float* hb = &hfull[b][wv << 5];
                float4 a0 = {0.f,0.f,0.f,0.f}, a1 = a0, a2 = a0, a3 = a0;
                DOTALL
                lds_part[b][wv][u] = make_float4(hsum4(a0), hsum4(a1),
                                                 hsum4(a2), hsum4(a3));
            }
        }
        __syncthreads();   // G

        // H: update (wave b owns batch b); publish h via relaxed atomic store
        if (wv < 2) {
            bool act = t < len4[wv];
            float pi, pf, pg, po;
            if (tt > 0 && act) {
                float4 q0 = lds_part[wv][0][u], q1 = lds_part[wv][1][u];
                float4 q2 = lds_part[wv][2][u], q3 = lds_part[wv][3][u];
                float4 q4 = lds_part[wv][4][u], q5 = lds_part[wv][5][u];
                float4 q6 = lds_part[wv][6][u], q7 = lds_part[wv][7][u];
                pi = q0.x+q1.x+q2.x+q3.x+q4.x+q5.x+q6.x+q7.x + x0;
                pf = q0.y+q1.y+q2.y+q3.y+q4.y+q5.y+q6.y+q7.y + x1;
                pg = q0.z+q1.z+q2.z+q3.z+q4.z+q5.z+q6.z+q7.z + x2;
                po = q0.w+q1.w+q2.w+q3.w+q4.w+q5.w+q6.w+q7.w + x3;
            } else {
                pi = x0; pf = x1; pg = x2; po = x3;
            }
            float h_old = hfull[wv][(s << 6) + u];
            float hv = h_old;
            if (act) {
                float gi = sigf(pi), gf = sigf(pf), gg = tanhf(pg), go = sigf(po);
                c_state = gf * c_state + gi * gg;
                hv = go * tanhf(c_state);
            }
            hfull[wv][(s << 6) + u] = hv;
            __hip_atomic_store(hwp + (size_t)t * hstr, hv,
                               __ATOMIC_RELAXED, __HIP_MEMORY_SCOPE_AGENT);
        }
        __syncthreads();   // I: all h atomic stores complete (vmcnt drain)

        // J: relaxed flag release (wave 0 lanes 0..1)
        if (wv == 0 && u < 2)
            __hip_atomic_store(flrelW0 + tt, 1, __ATOMIC_RELAXED,
                               __HIP_MEMORY_SCOPE_AGENT);
    }
}

// ---------------------------------------------------------------------------
// Classifier GEMM
// ---------------------------------------------------------------------------
__global__ __launch_bounds__(256, 4)
void k_clf(const float* __restrict__ hsF, const float* __restrict__ hsB,
           int hstr, const float* __restrict__ Wclf, const float* __restrict__ bclf,
           float* __restrict__ logits) {
    __shared__ float wt[512 * 32];
    __shared__ float xt[32 * 128];
    int tid = threadIdx.x;
    int r0 = blockIdx.x << 7;
    #pragma unroll
    for (int e = 0; e < 64; ++e) {
        int idx = e * 256 + tid;
        int kk = idx >> 9, j = idx & 511;
        wt[j * 32 + kk] = Wclf[idx];
    }
    int rl = tid >> 1, half = tid & 1;
    int kk = tid & 31, rg = tid >> 5;
    float acc[16] = {};
    for (int jc = 0; jc < 16; ++jc) {
        const float* src = (jc < 8 ? hsF : hsB) +
                           (size_t)(r0 + rl) * hstr + ((jc & 7) << 5) + (half << 4);
        float4 v0 = *(const float4*)(src + 0);
        float4 v1 = *(const float4*)(src + 4);
        float4 v2 = *(const float4*)(src + 8);
        float4 v3 = *(const float4*)(src + 12);
        __syncthreads();
        int jb = half << 4;
        xt[(jb+ 0)*128 + rl] = v0.x; xt[(jb+ 1)*128 + rl] = v0.y;
        xt[(jb+ 2)*128 + rl] = v0.z; xt[(jb+ 3)*128 + rl] = v0.w;
        xt[(jb+ 4)*128 + rl] = v1.x; xt[(jb+ 5)*128 + rl] = v1.y;
        xt[(jb+ 6)*128 + rl] = v1.z; xt[(jb+ 7)*128 + rl] = v1.w;
        xt[(jb+ 8)*128 + rl] = v2.x; xt[(jb+ 9)*128 + rl] = v2.y;
        xt[(jb+10)*128 + rl] = v2.z; xt[(jb+11)*128 + rl] = v2.w;
        xt[(jb+12)*128 + rl] = v3.x; xt[(jb+13)*128 + rl] = v3.y;
        xt[(jb+14)*128 + rl] = v3.z; xt[(jb+15)*128 + rl] = v3.w;
        __syncthreads();
        #pragma unroll
        for (int jp = 0; jp < 32; ++jp) {
            float w = wt[(jc * 32 + jp) * 32 + kk];
            const float* xr = &xt[jp * 128 + rg * 16];
            float4 x0 = *(const float4*)(xr + 0);
            float4 x1 = *(const float4*)(xr + 4);
            float4 x2 = *(const float4*)(xr + 8);
            float4 x3 = *(const float4*)(xr + 12);
            acc[ 0] += x0.x*w; acc[ 1] += x0.y*w; acc[ 2] += x0.z*w; acc[ 3] += x0.w*w;
            acc[ 4] += x1.x*w; acc[ 5] += x1.y*w; acc[ 6] += x1.z*w; acc[ 7] += x1.w*w;
            acc[ 8] += x2.x*w; acc[ 9] += x2.y*w; acc[10] += x2.z*w; acc[11] += x2.w*w;
            acc[12] += x3.x*w; acc[13] += x3.y*w; acc[14] += x3.z*w; acc[15] += x3.w*w;
        }
    }
    float bb = bclf[kk];
    #pragma unroll
    for (int i = 0; i < 16; ++i)
        logits[(size_t)(r0 + rg * 16 + i) * NK + kk] = acc[i] + bb;
}

// ---------------------------------------------------------------------------
// Viterbi: one wave per batch, ref-exact rounding order
// ---------------------------------------------------------------------------
__global__ __launch_bounds__(64)
void k_viterbi(const float* __restrict__ logits, const int* __restrict__ lengths,
               const float* __restrict__ st, const float* __restrict__ et,
               const float* __restrict__ trans, float* __restrict__ preds) {
    int b = blockIdx.x, lane = threadIdx.x;
    __shared__ unsigned char hist[NT - 1][NK];
    int len = lengths[b];
    int k = lane & 31;
    float wt[32];
    #pragma unroll
    for (int j = 0; j < 32; ++j) wt[j] = trans[j * NK + k];
    const float* lg = logits + (size_t)b * NT * NK;
    float score = st[k] + lg[k];
    for (int t = 1; t < NT; ++t) {
        float emis = lg[t * NK + k];
        float best = -3.4e38f; int bidx = 0;
        #pragma unroll
        for (int j = 0; j < 32; ++j) {
            float cand = (__shfl(score, j, 64) + wt[j]) + emis;
            if (cand > best) { best = cand; bidx = j; }
        }
        bool m = t < len;
        if (lane < 32) hist[t - 1][k] = (unsigned char)(m ? bidx : k);
        score = m ? best : score;
    }
    score += et[k];
    float bv = -3.4e38f; int btag = 0;
    #pragma unroll
    for (int j = 0; j < 32; ++j) {
        float v = __shfl(score, j, 64);
        if (v > bv) { bv = v; btag = j; }
    }
    __syncthreads();
    if (lane == 0) {
        int tag = btag;
        for (int t = NT - 1; t >= 1; --t) {
            preds[(size_t)b * NT + t] = (t < len) ? (float)tag : 0.f;
            tag = hist[t - 1][tag];
        }
        preds[(size_t)b * NT] = (float)tag;
    }
}

// ---------------------------------------------------------------------------
extern "C" void kernel_launch(void* const* d_in, const int* in_sizes, int n_in,
                              void* d_out, int out_size, void* d_ws, size_t ws_size,
                              hipStream_t stream) {
    (void)in_sizes; (void)n_in; (void)out_size;
    const float* x       = (const float*)d_in[0];
    const int*   lengths = (const int*)d_in[1];
    const float* Wih_f = (const float*)d_in[3];
    const float* Whh_f = (const float*)d_in[4];
    const float* b_f   = (const float*)d_in[5];
    const float* Wih_b = (const float*)d_in[6];
    const float* Whh_b = (const float*)d_in[7];
    const float* b_b   = (const float*)d_in[8];
    const float* W_clf = (const float*)d_in[9];
    const float* b_clf = (const float*)d_in[10];
    const float* st    = (const float*)d_in[11];
    const float* et    = (const float*)d_in[12];
    const float* trans = (const float*)d_in[13];

    float* logits = (float*)d_out;
    float* preds  = logits + (size_t)NBT * NK;

    // scratch inside the (not-yet-written) logits region of d_out (4 MB):
    // ww 2 MB @0; flags 1 MB @2MB. k_clf overwrites both later.
    float* wwp = logits;
    int*   flg = (int*)(logits + 524288);
    const size_t FLB = (size_t)262144 * 4;            // 2*64*4*512 ints

    const size_t XPB = (size_t)NBT * NG * 4;          // 134,217,728
    bool conc = ws_size >= 2 * XPB;

    char* ws = (char*)d_ws;
    float* xp0 = (float*)ws;
    float* xp1 = conc ? (float*)(ws + XPB) : xp0;
    float *hsF, *hsB; int hstr;
    if (conc) {
        hsF = xp0; hsB = xp1; hstr = NG;              // h aliases gate-i columns
    } else {
        hsF = (float*)(ws + XPB); hsB = hsF + (size_t)NB * NT * NH; hstr = NH;
    }

    hipMemsetAsync(flg, 0, FLB, stream);
    k_wprep3<<<2048, 256, 0, stream>>>(Whh_f, Whh_b, wwp);

    if (conc) {
        k_gemm4<<<dim3(16, 256), 256, 0, stream>>>(x, Wih_f, Wih_b, b_f, b_b,
                                                   xp0, xp1, 0);
        k_lstm4b<<<256, 512, 0, stream>>>(xp0, xp1, wwp, lengths,
                                          hsF, hsB, hstr, flg, 0);
    } else {
        k_gemm4<<<dim3(8, 256), 256, 0, stream>>>(x, Wih_f, Wih_b, b_f, b_b,
                                                  xp0, xp0, 0);
        k_lstm4b<<<128, 512, 0, stream>>>(xp0, xp0, wwp, lengths,
                                          hsF, hsB, hstr, flg, 0);
        k_gemm4<<<dim3(8, 256), 256, 0, stream>>>(x, Wih_f, Wih_b, b_f, b_b,
                                                  xp0, xp0, 8);
        k_lstm4b<<<128, 512, 0, stream>>>(xp0, xp0, wwp, lengths,
                                          hsF, hsB, hstr, flg, 32);
    }
    k_clf<<<256, 256, 0, stream>>>(hsF, hsB, hstr, W_clf, b_clf, logits);
    k_viterbi<<<NB, 64, 0, stream>>>(logits, lengths, st, et, trans, preds);
}

// Round 17
// 2246.934 us; speedup vs baseline: 1.2465x; 1.2465x over previous
//
#include <hip/hip_runtime.h>
#include <math.h>

#define NB 64
#define NT 512
#define ND 512
#define NH 256
#define NG 1024   // 4*H
#define NK 32
#define NBT (NB*NT)

typedef __attribute__((ext_vector_type(8))) short short8;
typedef __attribute__((ext_vector_type(4))) float f32x4;

__device__ __forceinline__ float sigf(float x) { return 1.f / (1.f + expf(-x)); }
__device__ __forceinline__ float hsum4(float4 v) { return v.x + v.y + v.z + v.w; }

__device__ __forceinline__ unsigned short f2bf(float f) {
    unsigned u = __float_as_uint(f);
    unsigned r = u + 0x7FFF + ((u >> 16) & 1);   // RNE to bf16
    return (unsigned short)(r >> 16);
}
__device__ __forceinline__ float bf2f(unsigned short s) {
    return __uint_as_float((unsigned)s << 16);
}

// ---------------------------------------------------------------------------
// Weight prep (round-8 layout):
// ww[(((dir*4+s)*32 + g*8+j)*512 + tid)*4 + e] = Whh_dir[g*256+s*64+u][part*32+j*4+e]
// ---------------------------------------------------------------------------
__global__ void k_wprep3(const float* __restrict__ Wf, const float* __restrict__ Wb,
                         float* __restrict__ ww) {
    int f = blockIdx.x * 256 + threadIdx.x;      // 0 .. 524287
    int e   = f & 3;
    int tid = (f >> 2) & 511;
    int gj  = (f >> 11) & 31;
    int s   = (f >> 16) & 3;
    int dir = (f >> 18) & 1;
    int u = tid & 63, part = tid >> 6;
    int g = gj >> 3, j = gj & 7;
    const float* W = dir ? Wb : Wf;
    int row = g * 256 + s * 64 + u;
    int col = part * 32 + j * 4 + e;
    ww[f] = W[row * 256 + col];
}

// ---------------------------------------------------------------------------
// Input projection GEMM via MFMA, split-bf16 3-term (xp error ~1e-5):
// 128x128 tile, 512 threads = 8 waves of 32x64; K chunks of 32;
// v_mfma_f32_16x16x32_bf16. A/B frag: row/col = lane&15, k=(lane>>4)*8+e
// (contiguous); C/D: col = lane&15, row = (lane>>4)*4 + reg.
// LDS tiles stride 40 bf16 (80 B): 16B-aligned b128 reads, <=2-way banks.
// ---------------------------------------------------------------------------
__global__ void
__attribute__((amdgpu_flat_work_group_size(512, 512)))
k_gemmM(const float* __restrict__ x, const float* __restrict__ Wf,
        const float* __restrict__ Wb, const float* __restrict__ bf,
        const float* __restrict__ bb, float* __restrict__ xpF,
        float* __restrict__ xpB, int bxBase) {
    __shared__ unsigned short Ahi[128 * 40], Alo[128 * 40];
    __shared__ unsigned short Bhi[128 * 40], Blo[128 * 40];
    int tid = threadIdx.x;
    int bx = blockIdx.x + bxBase;
    int dir = bx >> 3;
    const float* W    = dir ? Wb : Wf;
    const float* bias = dir ? bb : bf;
    float* xp         = dir ? xpB : xpF;
    size_t r0 = (size_t)blockIdx.y << 7;
    int c0 = (bx & 7) << 7;

    int srow = tid >> 2, sk = (tid & 3) << 3;    // staging row, k-offset
    const float* xs = x + (r0 + srow) * ND + sk;
    const float* wsr = W + (size_t)(c0 + srow) * ND + sk;
    int sb = srow * 40 + sk;                     // LDS base (bf16 units)

    int lane = tid & 63;
    int wv = tid >> 6;                           // 8 waves
    int wm = wv & 3;                             // m-quad (rows wm*32)
    int wn = wv >> 2;                            // n-half (cols wn*64)
    int frow = lane & 15;
    int fk = (lane >> 4) << 3;

    f32x4 acc[2][4];
    #pragma unroll
    for (int i = 0; i < 2; ++i)
        #pragma unroll
        for (int j = 0; j < 4; ++j)
            acc[i][j] = (f32x4){0.f, 0.f, 0.f, 0.f};

    for (int kt = 0; kt < ND; kt += 32) {
        // ---- stage x & W chunk as split bf16 (each thread: 8 elems each)
        float4 v0 = *(const float4*)(xs + kt);
        float4 v1 = *(const float4*)(xs + kt + 4);
        float4 w0 = *(const float4*)(wsr + kt);
        float4 w1 = *(const float4*)(wsr + kt + 4);
        float xv[8]  = {v0.x, v0.y, v0.z, v0.w, v1.x, v1.y, v1.z, v1.w};
        float wvv[8] = {w0.x, w0.y, w0.z, w0.w, w1.x, w1.y, w1.z, w1.w};
        short8 xh, xl, wh, wl;
        #pragma unroll
        for (int e = 0; e < 8; ++e) {
            unsigned short h = f2bf(xv[e]);
            xh[e] = (short)h;
            xl[e] = (short)f2bf(xv[e] - bf2f(h));
            unsigned short g = f2bf(wvv[e]);
            wh[e] = (short)g;
            wl[e] = (short)f2bf(wvv[e] - bf2f(g));
        }
        __syncthreads();                 // prev chunk's frag reads done
        *(short8*)&Ahi[sb] = xh;  *(short8*)&Alo[sb] = xl;
        *(short8*)&Bhi[sb] = wh;  *(short8*)&Blo[sb] = wl;
        __syncthreads();                 // staging visible

        // ---- fragments
        short8 ah[2], al[2], bh[4], bl[4];
        #pragma unroll
        for (int mi = 0; mi < 2; ++mi) {
            int ar = (wm * 32 + mi * 16 + frow) * 40 + fk;
            ah[mi] = *(const short8*)&Ahi[ar];
            al[mi] = *(const short8*)&Alo[ar];
        }
        #pragma unroll
        for (int ni = 0; ni < 4; ++ni) {
            int br = (wn * 64 + ni * 16 + frow) * 40 + fk;
            bh[ni] = *(const short8*)&Bhi[br];
            bl[ni] = *(const short8*)&Blo[br];
        }
        // ---- 3-term MFMA
        #pragma unroll
        for (int mi = 0; mi < 2; ++mi)
            #pragma unroll
            for (int ni = 0; ni < 4; ++ni) {
                acc[mi][ni] = __builtin_amdgcn_mfma_f32_16x16x32_bf16(
                    ah[mi], bh[ni], acc[mi][ni], 0, 0, 0);
                acc[mi][ni] = __builtin_amdgcn_mfma_f32_16x16x32_bf16(
                    ah[mi], bl[ni], acc[mi][ni], 0, 0, 0);
                acc[mi][ni] = __builtin_amdgcn_mfma_f32_16x16x32_bf16(
                    al[mi], bh[ni], acc[mi][ni], 0, 0, 0);
            }
    }

    // ---- epilogue: D row = (lane>>4)*4 + r, col = lane&15
    #pragma unroll
    for (int mi = 0; mi < 2; ++mi)
        #pragma unroll
        for (int ni = 0; ni < 4; ++ni) {
            int orow = wm * 32 + mi * 16 + ((lane >> 4) << 2);
            int ocol = c0 + wn * 64 + ni * 16 + frow;
            float bb2 = bias[ocol];
            float* ob = xp + (r0 + orow) * NG + ocol;
            #pragma unroll
            for (int r = 0; r < 4; ++r)
                ob[(size_t)r * NG] = acc[mi][ni][r] + bb2;
        }
}

// ---------------------------------------------------------------------------
// lstm macros (round-8)
// ---------------------------------------------------------------------------
#define FMA4(A, W, H) { (A).x += (W).x*(H).x; (A).y += (W).y*(H).y; \
                        (A).z += (W).z*(H).z; (A).w += (W).w*(H).w; }

#define DECLR(g) \
    float4 wr##g##_0 = wwp[qb + ((g)*8+0)*512]; \
    float4 wr##g##_1 = wwp[qb + ((g)*8+1)*512]; \
    float4 wr##g##_2 = wwp[qb + ((g)*8+2)*512]; \
    float4 wr##g##_3 = wwp[qb + ((g)*8+3)*512]; \
    float4 wr##g##_4 = wwp[qb + ((g)*8+4)*512];

#define DOTRJ(j) { float4 h_ = *(const float4*)(hb + (j)*4); \
    FMA4(a0, wr0_##j, h_) FMA4(a1, wr1_##j, h_) \
    FMA4(a2, wr2_##j, h_) FMA4(a3, wr3_##j, h_) }

#define DOTLJ(jj, j) { float4 h_ = *(const float4*)(hb + (j)*4); \
    { float4 l_ = lds_w[(0*3+(jj))*512 + tid]; FMA4(a0, l_, h_) } \
    { float4 l_ = lds_w[(1*3+(jj))*512 + tid]; FMA4(a1, l_, h_) } \
    { float4 l_ = lds_w[(2*3+(jj))*512 + tid]; FMA4(a2, l_, h_) } \
    { float4 l_ = lds_w[(3*3+(jj))*512 + tid]; FMA4(a3, l_, h_) } }

#define DOTALL DOTRJ(0) DOTRJ(1) DOTRJ(2) DOTRJ(3) DOTRJ(4) \
               DOTLJ(0,5) DOTLJ(1,6) DOTLJ(2,7)

// ---------------------------------------------------------------------------
// LSTM recurrence — round-15 k_lstm4b VERBATIM (best measured: 1650 us).
// ---------------------------------------------------------------------------
__global__ void
__attribute__((amdgpu_flat_work_group_size(512, 512)))
k_lstm4b(const float* __restrict__ xpF, const float* __restrict__ xpB,
         const float* __restrict__ ww, const int* __restrict__ lengths,
         float* hsF, float* hsB, int hstr, int* flags, int gBase) {
    int bi = blockIdx.x;
    int g   = (bi & 7) + 8 * (bi >> 5) + gBase;  // 0..63: dir*32 + group
    int s   = (bi >> 3) & 3;                     // u-slice; siblings share bi&7
    int dir = g >> 5;
    int b0  = (g & 31) * 2;
    const float* xp = dir ? xpB : xpF;
    float* hsD      = dir ? hsB : hsF;

    int tid = threadIdx.x;
    int u  = tid & 63;
    int wv = tid >> 6;                           // wave = v-chunk (part) 0..7

    __shared__ float4 lds_w[12 * 512];           // 96 KB
    __shared__ __align__(16) float hfull[2][256];
    __shared__ float4 lds_part[2][8][64];        // 16 KB
    __shared__ int len4[2];

    const float4* wwp = (const float4*)ww;
    int qb = ((dir * 4 + s) * 32) * 512 + tid;

    DECLR(0) DECLR(1) DECLR(2) DECLR(3)          // 20 named quads -> VGPRs
    #pragma unroll
    for (int gg = 0; gg < 4; ++gg)
        #pragma unroll
        for (int jj = 0; jj < 3; ++jj)
            lds_w[(gg * 3 + jj) * 512 + tid] = wwp[qb + (gg * 8 + 5 + jj) * 512];

    if (tid < 2) len4[tid] = lengths[b0 + tid];
    ((float*)hfull)[tid] = 0.f;                  // 512 floats exactly
    float c_state = 0.f;
    __syncthreads();

    // staging assignment (threads 0..191): 96 ulongs per batch
    int sb   = (tid < 192) ? (tid / 96) : 0;     // batch 0..1
    int sr   = tid - sb * 96;
    int spsi = (sr >> 5) & 3, sq = sr & 31;
    int ssl  = spsi + (spsi >= s);               // partner slice
    unsigned long long* sdst =
        (unsigned long long*)&hfull[sb & 1][ssl * 64 + sq * 2];
    const float* ssrc0 = hsD + (size_t)(b0 + (sb & 1)) * NT * hstr + ssl * 64 + sq * 2;

    // poller assignment (threads 0..7): (pb, ps)
    int pb = tid & 1, ps = (tid >> 1) & 3;
    const int* pollp = flags + ((((dir << 6) + b0 + pb) << 2) + ps) * 512;

    // update-wave global h pointer (waves 0..1)
    float* hwp = hsD + (size_t)(b0 + (wv & 1)) * NT * hstr + (s << 6) + u;
    // release flag pointer (wave 0 lanes 0..1: u = batch)
    int* flrelW0 = flags + ((((dir << 6) + b0 + (u & 1)) << 2) + s) * 512;

    for (int tt = 0; tt < NT; ++tt) {
        int t = dir ? (NT - 1 - tt) : tt;

        // A: xp prefetch (waves 0..1, batch wv's 4 gate columns)
        float x0 = 0.f, x1 = 0.f, x2 = 0.f, x3 = 0.f;
        if (wv < 2) {
            const float* xr = xp + ((size_t)(b0 + wv) * NT + t) * NG + (s << 6) + u;
            x0 = xr[0]; x1 = xr[256]; x2 = xr[512]; x3 = xr[768];
        }
        // B: poll partner flags RELAXED
        if (tt > 0 && tid < 8 && ps != s && t < len4[pb]) {
            const int* fp = pollp + (tt - 1);
            while (__hip_atomic_load(fp, __ATOMIC_RELAXED,
                                     __HIP_MEMORY_SCOPE_AGENT) == 0) {}
        }
        __syncthreads();   // C: flag loads complete block-wide

        // D: stage partner h via 64-bit relaxed atomic loads
        if (tt > 0 && tid < 192 && t < len4[sb]) {
            int t_prev = dir ? (t + 1) : (t - 1);
            unsigned long long v = __hip_atomic_load(
                (const unsigned long long*)(ssrc0 + (size_t)t_prev * hstr),
                __ATOMIC_RELAXED, __HIP_MEMORY_SCOPE_AGENT);
            *sdst = v;
        }
        __syncthreads();   // E

        // F: 2 dots (block-uniform skip per batch)
        #pragma unroll
        for (int b = 0; b < 2; ++b) {
            if (tt > 0 && t < len4[b]) {
                const float* hb = &hfull[b][wv << 5];
                float4 a0 = {0.f,0.f,0.f,0.f}, a1 = a0, a2 = a0, a3 = a0;
                DOTALL
                lds_part[b][wv][u] = make_float4(hsum4(a0), hsum4(a1),
                                                 hsum4(a2), hsum4(a3));
            }
        }
        __syncthreads();   // G

        // H: update (wave b owns batch b); publish h via relaxed atomic store
        if (wv < 2) {
            bool act = t < len4[wv];
            float pi, pf, pg, po;
            if (tt > 0 && act) {
                float4 q0 = lds_part[wv][0][u], q1 = lds_part[wv][1][u];
                float4 q2 = lds_part[wv][2][u], q3 = lds_part[wv][3][u];
                float4 q4 = lds_part[wv][4][u], q5 = lds_part[wv][5][u];
                float4 q6 = lds_part[wv][6][u], q7 = lds_part[wv][7][u];
                pi = q0.x+q1.x+q2.x+q3.x+q4.x+q5.x+q6.x+q7.x + x0;
                pf = q0.y+q1.y+q2.y+q3.y+q4.y+q5.y+q6.y+q7.y + x1;
                pg = q0.z+q1.z+q2.z+q3.z+q4.z+q5.z+q6.z+q7.z + x2;
                po = q0.w+q1.w+q2.w+q3.w+q4.w+q5.w+q6.w+q7.w + x3;
            } else {
                pi = x0; pf = x1; pg = x2; po = x3;
            }
            float h_old = hfull[wv][(s << 6) + u];
            float hv = h_old;
            if (act) {
                float gi = sigf(pi), gf = sigf(pf), gg = tanhf(pg), go = sigf(po);
                c_state = gf * c_state + gi * gg;
                hv = go * tanhf(c_state);
            }
            hfull[wv][(s << 6) + u] = hv;
            __hip_atomic_store(hwp + (size_t)t * hstr, hv,
                               __ATOMIC_RELAXED, __HIP_MEMORY_SCOPE_AGENT);
        }
        __syncthreads();   // I: all h atomic stores complete (vmcnt drain)

        // J: relaxed flag release (wave 0 lanes 0..1)
        if (wv == 0 && u < 2)
            __hip_atomic_store(flrelW0 + tt, 1, __ATOMIC_RELAXED,
                               __HIP_MEMORY_SCOPE_AGENT);
    }
}

// ---------------------------------------------------------------------------
// Classifier GEMM
// ---------------------------------------------------------------------------
__global__ __launch_bounds__(256, 4)
void k_clf(const float* __restrict__ hsF, const float* __restrict__ hsB,
           int hstr, const float* __restrict__ Wclf, const float* __restrict__ bclf,
           float* __restrict__ logits) {
    __shared__ float wt[512 * 32];
    __shared__ float xt[32 * 128];
    int tid = threadIdx.x;
    int r0 = blockIdx.x << 7;
    #pragma unroll
    for (int e = 0; e < 64; ++e) {
        int idx = e * 256 + tid;
        int kk = idx >> 9, j = idx & 511;
        wt[j * 32 + kk] = Wclf[idx];
    }
    int rl = tid >> 1, half = tid & 1;
    int kk = tid & 31, rg = tid >> 5;
    float acc[16] = {};
    for (int jc = 0; jc < 16; ++jc) {
        const float* src = (jc < 8 ? hsF : hsB) +
                           (size_t)(r0 + rl) * hstr + ((jc & 7) << 5) + (half << 4);
        float4 v0 = *(const float4*)(src + 0);
        float4 v1 = *(const float4*)(src + 4);
        float4 v2 = *(const float4*)(src + 8);
        float4 v3 = *(const float4*)(src + 12);
        __syncthreads();
        int jb = half << 4;
        xt[(jb+ 0)*128 + rl] = v0.x; xt[(jb+ 1)*128 + rl] = v0.y;
        xt[(jb+ 2)*128 + rl] = v0.z; xt[(jb+ 3)*128 + rl] = v0.w;
        xt[(jb+ 4)*128 + rl] = v1.x; xt[(jb+ 5)*128 + rl] = v1.y;
        xt[(jb+ 6)*128 + rl] = v1.z; xt[(jb+ 7)*128 + rl] = v1.w;
        xt[(jb+ 8)*128 + rl] = v2.x; xt[(jb+ 9)*128 + rl] = v2.y;
        xt[(jb+10)*128 + rl] = v2.z; xt[(jb+11)*128 + rl] = v2.w;
        xt[(jb+12)*128 + rl] = v3.x; xt[(jb+13)*128 + rl] = v3.y;
        xt[(jb+14)*128 + rl] = v3.z; xt[(jb+15)*128 + rl] = v3.w;
        __syncthreads();
        #pragma unroll
        for (int jp = 0; jp < 32; ++jp) {
            float w = wt[(jc * 32 + jp) * 32 + kk];
            const float* xr = &xt[jp * 128 + rg * 16];
            float4 x0 = *(const float4*)(xr + 0);
            float4 x1 = *(const float4*)(xr + 4);
            float4 x2 = *(const float4*)(xr + 8);
            float4 x3 = *(const float4*)(xr + 12);
            acc[ 0] += x0.x*w; acc[ 1] += x0.y*w; acc[ 2] += x0.z*w; acc[ 3] += x0.w*w;
            acc[ 4] += x1.x*w; acc[ 5] += x1.y*w; acc[ 6] += x1.z*w; acc[ 7] += x1.w*w;
            acc[ 8] += x2.x*w; acc[ 9] += x2.y*w; acc[10] += x2.z*w; acc[11] += x2.w*w;
            acc[12] += x3.x*w; acc[13] += x3.y*w; acc[14] += x3.z*w; acc[15] += x3.w*w;
        }
    }
    float bb = bclf[kk];
    #pragma unroll
    for (int i = 0; i < 16; ++i)
        logits[(size_t)(r0 + rg * 16 + i) * NK + kk] = acc[i] + bb;
}

// ---------------------------------------------------------------------------
// Viterbi: one wave per batch, ref-exact rounding order
// ---------------------------------------------------------------------------
__global__ __launch_bounds__(64)
void k_viterbi(const float* __restrict__ logits, const int* __restrict__ lengths,
               const float* __restrict__ st, const float* __restrict__ et,
               const float* __restrict__ trans, float* __restrict__ preds) {
    int b = blockIdx.x, lane = threadIdx.x;
    __shared__ unsigned char hist[NT - 1][NK];
    int len = lengths[b];
    int k = lane & 31;
    float wt[32];
    #pragma unroll
    for (int j = 0; j < 32; ++j) wt[j] = trans[j * NK + k];
    const float* lg = logits + (size_t)b * NT * NK;
    float score = st[k] + lg[k];
    for (int t = 1; t < NT; ++t) {
        float emis = lg[t * NK + k];
        float best = -3.4e38f; int bidx = 0;
        #pragma unroll
        for (int j = 0; j < 32; ++j) {
            float cand = (__shfl(score, j, 64) + wt[j]) + emis;
            if (cand > best) { best = cand; bidx = j; }
        }
        bool m = t < len;
        if (lane < 32) hist[t - 1][k] = (unsigned char)(m ? bidx : k);
        score = m ? best : score;
    }
    score += et[k];
    float bv = -3.4e38f; int btag = 0;
    #pragma unroll
    for (int j = 0; j < 32; ++j) {
        float v = __shfl(score, j, 64);
        if (v > bv) { bv = v; btag = j; }
    }
    __syncthreads();
    if (lane == 0) {
        int tag = btag;
        for (int t = NT - 1; t >= 1; --t) {
            preds[(size_t)b * NT + t] = (t < len) ? (float)tag : 0.f;
            tag = hist[t - 1][tag];
        }
        preds[(size_t)b * NT] = (float)tag;
    }
}

// ---------------------------------------------------------------------------
extern "C" void kernel_launch(void* const* d_in, const int* in_sizes, int n_in,
                              void* d_out, int out_size, void* d_ws, size_t ws_size,
                              hipStream_t stream) {
    (void)in_sizes; (void)n_in; (void)out_size;
    const float* x       = (const float*)d_in[0];
    const int*   lengths = (const int*)d_in[1];
    const float* Wih_f = (const float*)d_in[3];
    const float* Whh_f = (const float*)d_in[4];
    const float* b_f   = (const float*)d_in[5];
    const float* Wih_b = (const float*)d_in[6];
    const float* Whh_b = (const float*)d_in[7];
    const float* b_b   = (const float*)d_in[8];
    const float* W_clf = (const float*)d_in[9];
    const float* b_clf = (const float*)d_in[10];
    const float* st    = (const float*)d_in[11];
    const float* et    = (const float*)d_in[12];
    const float* trans = (const float*)d_in[13];

    float* logits = (float*)d_out;
    float* preds  = logits + (size_t)NBT * NK;

    // scratch inside the (not-yet-written) logits region of d_out (4 MB):
    // ww 2 MB @0; flags 1 MB @2MB. k_clf overwrites both later.
    float* wwp = logits;
    int*   flg = (int*)(logits + 524288);
    const size_t FLB = (size_t)262144 * 4;            // 2*64*4*512 ints

    const size_t XPB = (size_t)NBT * NG * 4;          // 134,217,728
    bool conc = ws_size >= 2 * XPB;

    char* ws = (char*)d_ws;
    float* xp0 = (float*)ws;
    float* xp1 = conc ? (float*)(ws + XPB) : xp0;
    float *hsF, *hsB; int hstr;
    if (conc) {
        hsF = xp0; hsB = xp1; hstr = NG;              // h aliases gate-i columns
    } else {
        hsF = (float*)(ws + XPB); hsB = hsF + (size_t)NB * NT * NH; hstr = NH;
    }

    hipMemsetAsync(flg, 0, FLB, stream);
    k_wprep3<<<2048, 256, 0, stream>>>(Whh_f, Whh_b, wwp);

    if (conc) {
        k_gemmM<<<dim3(16, 256), 512, 0, stream>>>(x, Wih_f, Wih_b, b_f, b_b,
                                                   xp0, xp1, 0);
        k_lstm4b<<<256, 512, 0, stream>>>(xp0, xp1, wwp, lengths,
                                          hsF, hsB, hstr, flg, 0);
    } else {
        k_gemmM<<<dim3(8, 256), 512, 0, stream>>>(x, Wih_f, Wih_b, b_f, b_b,
                                                  xp0, xp0, 0);
        k_lstm4b<<<128, 512, 0, stream>>>(xp0, xp0, wwp, lengths,
                                          hsF, hsB, hstr, flg, 0);
        k_gemmM<<<dim3(8, 256), 512, 0, stream>>>(x, Wih_f, Wih_b, b_f, b_b,
                                                  xp0, xp0, 8);
        k_lstm4b<<<128, 512, 0, stream>>>(xp0, xp0, wwp, lengths,
                                          hsF, hsB, hstr, flg, 32);
    }
    k_clf<<<256, 256, 0, stream>>>(hsF, hsB, hstr, W_clf, b_clf, logits);
    k_viterbi<<<NB, 64, 0, stream>>>(logits, lengths, st, et, trans, preds);
}

// Round 18
// 2175.612 us; speedup vs baseline: 1.2874x; 1.0328x over previous
//
#include <hip/hip_runtime.h>
#include <math.h>

#define NB 64
#define NT 512
#define ND 512
#define NH 256
#define NG 1024   // 4*H
#define NK 32
#define NBT (NB*NT)

typedef __attribute__((ext_vector_type(8))) short short8;
typedef __attribute__((ext_vector_type(4))) float f32x4;

__device__ __forceinline__ float sigf(float x) { return 1.f / (1.f + expf(-x)); }
__device__ __forceinline__ float hsum4(float4 v) { return v.x + v.y + v.z + v.w; }

__device__ __forceinline__ unsigned short f2bf(float f) {
    unsigned u = __float_as_uint(f);
    unsigned r = u + 0x7FFF + ((u >> 16) & 1);   // RNE to bf16
    return (unsigned short)(r >> 16);
}
__device__ __forceinline__ float bf2f(unsigned short s) {
    return __uint_as_float((unsigned)s << 16);
}

// ---------------------------------------------------------------------------
// Weight prep (round-8 layout, unchanged):
// ww[(((dir*4+s)*32 + g*8+j)*512 + tid)*4 + e] = Whh_dir[g*256+s*64+u][part*32+j*4+e]
// ---------------------------------------------------------------------------
__global__ void k_wprep3(const float* __restrict__ Wf, const float* __restrict__ Wb,
                         float* __restrict__ ww) {
    int f = blockIdx.x * 256 + threadIdx.x;      // 0 .. 524287
    int e   = f & 3;
    int tid = (f >> 2) & 511;
    int gj  = (f >> 11) & 31;
    int s   = (f >> 16) & 3;
    int dir = (f >> 18) & 1;
    int u = tid & 63, part = tid >> 6;
    int g = gj >> 3, j = gj & 7;
    const float* W = dir ? Wb : Wf;
    int row = g * 256 + s * 64 + u;
    int col = part * 32 + j * 4 + e;
    ww[f] = W[row * 256 + col];
}

// ---------------------------------------------------------------------------
// Input projection GEMM via MFMA, split-bf16 3-term — round-17 VERBATIM.
// ---------------------------------------------------------------------------
__global__ void
__attribute__((amdgpu_flat_work_group_size(512, 512)))
k_gemmM(const float* __restrict__ x, const float* __restrict__ Wf,
        const float* __restrict__ Wb, const float* __restrict__ bf,
        const float* __restrict__ bb, float* __restrict__ xpF,
        float* __restrict__ xpB, int bxBase) {
    __shared__ unsigned short Ahi[128 * 40], Alo[128 * 40];
    __shared__ unsigned short Bhi[128 * 40], Blo[128 * 40];
    int tid = threadIdx.x;
    int bx = blockIdx.x + bxBase;
    int dir = bx >> 3;
    const float* W    = dir ? Wb : Wf;
    const float* bias = dir ? bb : bf;
    float* xp         = dir ? xpB : xpF;
    size_t r0 = (size_t)blockIdx.y << 7;
    int c0 = (bx & 7) << 7;

    int srow = tid >> 2, sk = (tid & 3) << 3;    // staging row, k-offset
    const float* xs = x + (r0 + srow) * ND + sk;
    const float* wsr = W + (size_t)(c0 + srow) * ND + sk;
    int sb = srow * 40 + sk;                     // LDS base (bf16 units)

    int lane = tid & 63;
    int wv = tid >> 6;                           // 8 waves
    int wm = wv & 3;                             // m-quad (rows wm*32)
    int wn = wv >> 2;                            // n-half (cols wn*64)
    int frow = lane & 15;
    int fk = (lane >> 4) << 3;

    f32x4 acc[2][4];
    #pragma unroll
    for (int i = 0; i < 2; ++i)
        #pragma unroll
        for (int j = 0; j < 4; ++j)
            acc[i][j] = (f32x4){0.f, 0.f, 0.f, 0.f};

    for (int kt = 0; kt < ND; kt += 32) {
        float4 v0 = *(const float4*)(xs + kt);
        float4 v1 = *(const float4*)(xs + kt + 4);
        float4 w0 = *(const float4*)(wsr + kt);
        float4 w1 = *(const float4*)(wsr + kt + 4);
        float xv[8]  = {v0.x, v0.y, v0.z, v0.w, v1.x, v1.y, v1.z, v1.w};
        float wvv[8] = {w0.x, w0.y, w0.z, w0.w, w1.x, w1.y, w1.z, w1.w};
        short8 xh, xl, wh, wl;
        #pragma unroll
        for (int e = 0; e < 8; ++e) {
            unsigned short h = f2bf(xv[e]);
            xh[e] = (short)h;
            xl[e] = (short)f2bf(xv[e] - bf2f(h));
            unsigned short g = f2bf(wvv[e]);
            wh[e] = (short)g;
            wl[e] = (short)f2bf(wvv[e] - bf2f(g));
        }
        __syncthreads();
        *(short8*)&Ahi[sb] = xh;  *(short8*)&Alo[sb] = xl;
        *(short8*)&Bhi[sb] = wh;  *(short8*)&Blo[sb] = wl;
        __syncthreads();

        short8 ah[2], al[2], bh[4], bl[4];
        #pragma unroll
        for (int mi = 0; mi < 2; ++mi) {
            int ar = (wm * 32 + mi * 16 + frow) * 40 + fk;
            ah[mi] = *(const short8*)&Ahi[ar];
            al[mi] = *(const short8*)&Alo[ar];
        }
        #pragma unroll
        for (int ni = 0; ni < 4; ++ni) {
            int br = (wn * 64 + ni * 16 + frow) * 40 + fk;
            bh[ni] = *(const short8*)&Bhi[br];
            bl[ni] = *(const short8*)&Blo[br];
        }
        #pragma unroll
        for (int mi = 0; mi < 2; ++mi)
            #pragma unroll
            for (int ni = 0; ni < 4; ++ni) {
                acc[mi][ni] = __builtin_amdgcn_mfma_f32_16x16x32_bf16(
                    ah[mi], bh[ni], acc[mi][ni], 0, 0, 0);
                acc[mi][ni] = __builtin_amdgcn_mfma_f32_16x16x32_bf16(
                    ah[mi], bl[ni], acc[mi][ni], 0, 0, 0);
                acc[mi][ni] = __builtin_amdgcn_mfma_f32_16x16x32_bf16(
                    al[mi], bh[ni], acc[mi][ni], 0, 0, 0);
            }
    }

    #pragma unroll
    for (int mi = 0; mi < 2; ++mi)
        #pragma unroll
        for (int ni = 0; ni < 4; ++ni) {
            int orow = wm * 32 + mi * 16 + ((lane >> 4) << 2);
            int ocol = c0 + wn * 64 + ni * 16 + frow;
            float bb2 = bias[ocol];
            float* ob = xp + (r0 + orow) * NG + ocol;
            #pragma unroll
            for (int r = 0; r < 4; ++r)
                ob[(size_t)r * NG] = acc[mi][ni][r] + bb2;
        }
}

// ---------------------------------------------------------------------------
// lstm macros — 24 named VGPR quads (j=0..5 per gate) + 8 LDS quads (j=6,7).
// Same j-ascending accumulation order as round 8/15: bit-identical h.
// ---------------------------------------------------------------------------
#define FMA4(A, W, H) { (A).x += (W).x*(H).x; (A).y += (W).y*(H).y; \
                        (A).z += (W).z*(H).z; (A).w += (W).w*(H).w; }

#define DECLR(g) \
    float4 wr##g##_0 = wwp[qb + ((g)*8+0)*512]; \
    float4 wr##g##_1 = wwp[qb + ((g)*8+1)*512]; \
    float4 wr##g##_2 = wwp[qb + ((g)*8+2)*512]; \
    float4 wr##g##_3 = wwp[qb + ((g)*8+3)*512]; \
    float4 wr##g##_4 = wwp[qb + ((g)*8+4)*512]; \
    float4 wr##g##_5 = wwp[qb + ((g)*8+5)*512];

#define DOTRJ(j) { float4 h_ = *(const float4*)(hb + (j)*4); \
    FMA4(a0, wr0_##j, h_) FMA4(a1, wr1_##j, h_) \
    FMA4(a2, wr2_##j, h_) FMA4(a3, wr3_##j, h_) }

#define DOTLJ(jj, j) { float4 h_ = *(const float4*)(hb + (j)*4); \
    { float4 l_ = lds_w[(0*2+(jj))*512 + tid]; FMA4(a0, l_, h_) } \
    { float4 l_ = lds_w[(1*2+(jj))*512 + tid]; FMA4(a1, l_, h_) } \
    { float4 l_ = lds_w[(2*2+(jj))*512 + tid]; FMA4(a2, l_, h_) } \
    { float4 l_ = lds_w[(3*2+(jj))*512 + tid]; FMA4(a3, l_, h_) } }

#define DOTALL DOTRJ(0) DOTRJ(1) DOTRJ(2) DOTRJ(3) DOTRJ(4) DOTRJ(5) \
               DOTLJ(0,6) DOTLJ(1,7)

// ---------------------------------------------------------------------------
// LSTM recurrence — round-15 k_lstm4b skeleton VERBATIM; only the weight
// register/LDS split changed (20+12 -> 24+8).
// ---------------------------------------------------------------------------
__global__ void
__attribute__((amdgpu_flat_work_group_size(512, 512)))
k_lstm4b(const float* __restrict__ xpF, const float* __restrict__ xpB,
         const float* __restrict__ ww, const int* __restrict__ lengths,
         float* hsF, float* hsB, int hstr, int* flags, int gBase) {
    int bi = blockIdx.x;
    int g   = (bi & 7) + 8 * (bi >> 5) + gBase;  // 0..63: dir*32 + group
    int s   = (bi >> 3) & 3;                     // u-slice; siblings share bi&7
    int dir = g >> 5;
    int b0  = (g & 31) * 2;
    const float* xp = dir ? xpB : xpF;
    float* hsD      = dir ? hsB : hsF;

    int tid = threadIdx.x;
    int u  = tid & 63;
    int wv = tid >> 6;                           // wave = v-chunk (part) 0..7

    __shared__ float4 lds_w[8 * 512];            // 64 KB (was 96)
    __shared__ __align__(16) float hfull[2][256];
    __shared__ float4 lds_part[2][8][64];        // 16 KB
    __shared__ int len4[2];

    const float4* wwp = (const float4*)ww;
    int qb = ((dir * 4 + s) * 32) * 512 + tid;

    DECLR(0) DECLR(1) DECLR(2) DECLR(3)          // 24 named quads -> VGPRs
    #pragma unroll
    for (int gg = 0; gg < 4; ++gg)
        #pragma unroll
        for (int jj = 0; jj < 2; ++jj)
            lds_w[(gg * 2 + jj) * 512 + tid] = wwp[qb + (gg * 8 + 6 + jj) * 512];

    if (tid < 2) len4[tid] = lengths[b0 + tid];
    ((float*)hfull)[tid] = 0.f;                  // 512 floats exactly
    float c_state = 0.f;
    __syncthreads();

    // staging assignment (threads 0..191): 96 ulongs per batch
    int sb   = (tid < 192) ? (tid / 96) : 0;     // batch 0..1
    int sr   = tid - sb * 96;
    int spsi = (sr >> 5) & 3, sq = sr & 31;
    int ssl  = spsi + (spsi >= s);               // partner slice
    unsigned long long* sdst =
        (unsigned long long*)&hfull[sb & 1][ssl * 64 + sq * 2];
    const float* ssrc0 = hsD + (size_t)(b0 + (sb & 1)) * NT * hstr + ssl * 64 + sq * 2;

    // poller assignment (threads 0..7): (pb, ps)
    int pb = tid & 1, ps = (tid >> 1) & 3;
    const int* pollp = flags + ((((dir << 6) + b0 + pb) << 2) + ps) * 512;

    // update-wave global h pointer (waves 0..1)
    float* hwp = hsD + (size_t)(b0 + (wv & 1)) * NT * hstr + (s << 6) + u;
    // release flag pointer (wave 0 lanes 0..1: u = batch)
    int* flrelW0 = flags + ((((dir << 6) + b0 + (u & 1)) << 2) + s) * 512;

    for (int tt = 0; tt < NT; ++tt) {
        int t = dir ? (NT - 1 - tt) : tt;

        // A: xp prefetch (waves 0..1, batch wv's 4 gate columns)
        float x0 = 0.f, x1 = 0.f, x2 = 0.f, x3 = 0.f;
        if (wv < 2) {
            const float* xr = xp + ((size_t)(b0 + wv) * NT + t) * NG + (s << 6) + u;
            x0 = xr[0]; x1 = xr[256]; x2 = xr[512]; x3 = xr[768];
        }
        // B: poll partner flags RELAXED
        if (tt > 0 && tid < 8 && ps != s && t < len4[pb]) {
            const int* fp = pollp + (tt - 1);
            while (__hip_atomic_load(fp, __ATOMIC_RELAXED,
                                     __HIP_MEMORY_SCOPE_AGENT) == 0) {}
        }
        __syncthreads();   // C: flag loads complete block-wide

        // D: stage partner h via 64-bit relaxed atomic loads
        if (tt > 0 && tid < 192 && t < len4[sb]) {
            int t_prev = dir ? (t + 1) : (t - 1);
            unsigned long long v = __hip_atomic_load(
                (const unsigned long long*)(ssrc0 + (size_t)t_prev * hstr),
                __ATOMIC_RELAXED, __HIP_MEMORY_SCOPE_AGENT);
            *sdst = v;
        }
        __syncthreads();   // E

        // F: 2 dots (block-uniform skip per batch)
        #pragma unroll
        for (int b = 0; b < 2; ++b) {
            if (tt > 0 && t < len4[b]) {
                const float* hb = &hfull[b][wv << 5];
                float4 a0 = {0.f,0.f,0.f,0.f}, a1 = a0, a2 = a0, a3 = a0;
                DOTALL
                lds_part[b][wv][u] = make_float4(hsum4(a0), hsum4(a1),
                                                 hsum4(a2), hsum4(a3));
            }
        }
        __syncthreads();   // G

        // H: update (wave b owns batch b); publish h via relaxed atomic store
        if (wv < 2) {
            bool act = t < len4[wv];
            float pi, pf, pg, po;
            if (tt > 0 && act) {
                float4 q0 = lds_part[wv][0][u], q1 = lds_part[wv][1][u];
                float4 q2 = lds_part[wv][2][u], q3 = lds_part[wv][3][u];
                float4 q4 = lds_part[wv][4][u], q5 = lds_part[wv][5][u];
                float4 q6 = lds_part[wv][6][u], q7 = lds_part[wv][7][u];
                pi = q0.x+q1.x+q2.x+q3.x+q4.x+q5.x+q6.x+q7.x + x0;
                pf = q0.y+q1.y+q2.y+q3.y+q4.y+q5.y+q6.y+q7.y + x1;
                pg = q0.z+q1.z+q2.z+q3.z+q4.z+q5.z+q6.z+q7.z + x2;
                po = q0.w+q1.w+q2.w+q3.w+q4.w+q5.w+q6.w+q7.w + x3;
            } else {
                pi = x0; pf = x1; pg = x2; po = x3;
            }
            float h_old = hfull[wv][(s << 6) + u];
            float hv = h_old;
            if (act) {
                float gi = sigf(pi), gf = sigf(pf), gg = tanhf(pg), go = sigf(po);
                c_state = gf * c_state + gi * gg;
                hv = go * tanhf(c_state);
            }
            hfull[wv][(s << 6) + u] = hv;
            __hip_atomic_store(hwp + (size_t)t * hstr, hv,
                               __ATOMIC_RELAXED, __HIP_MEMORY_SCOPE_AGENT);
        }
        __syncthreads();   // I: all h atomic stores complete (vmcnt drain)

        // J: relaxed flag release (wave 0 lanes 0..1)
        if (wv == 0 && u < 2)
            __hip_atomic_store(flrelW0 + tt, 1, __ATOMIC_RELAXED,
                               __HIP_MEMORY_SCOPE_AGENT);
    }
}

// ---------------------------------------------------------------------------
// Classifier GEMM
// ---------------------------------------------------------------------------
__global__ __launch_bounds__(256, 4)
void k_clf(const float* __restrict__ hsF, const float* __restrict__ hsB,
           int hstr, const float* __restrict__ Wclf, const float* __restrict__ bclf,
           float* __restrict__ logits) {
    __shared__ float wt[512 * 32];
    __shared__ float xt[32 * 128];
    int tid = threadIdx.x;
    int r0 = blockIdx.x << 7;
    #pragma unroll
    for (int e = 0; e < 64; ++e) {
        int idx = e * 256 + tid;
        int kk = idx >> 9, j = idx & 511;
        wt[j * 32 + kk] = Wclf[idx];
    }
    int rl = tid >> 1, half = tid & 1;
    int kk = tid & 31, rg = tid >> 5;
    float acc[16] = {};
    for (int jc = 0; jc < 16; ++jc) {
        const float* src = (jc < 8 ? hsF : hsB) +
                           (size_t)(r0 + rl) * hstr + ((jc & 7) << 5) + (half << 4);
        float4 v0 = *(const float4*)(src + 0);
        float4 v1 = *(const float4*)(src + 4);
        float4 v2 = *(const float4*)(src + 8);
        float4 v3 = *(const float4*)(src + 12);
        __syncthreads();
        int jb = half << 4;
        xt[(jb+ 0)*128 + rl] = v0.x; xt[(jb+ 1)*128 + rl] = v0.y;
        xt[(jb+ 2)*128 + rl] = v0.z; xt[(jb+ 3)*128 + rl] = v0.w;
        xt[(jb+ 4)*128 + rl] = v1.x; xt[(jb+ 5)*128 + rl] = v1.y;
        xt[(jb+ 6)*128 + rl] = v1.z; xt[(jb+ 7)*128 + rl] = v1.w;
        xt[(jb+ 8)*128 + rl] = v2.x; xt[(jb+ 9)*128 + rl] = v2.y;
        xt[(jb+10)*128 + rl] = v2.z; xt[(jb+11)*128 + rl] = v2.w;
        xt[(jb+12)*128 + rl] = v3.x; xt[(jb+13)*128 + rl] = v3.y;
        xt[(jb+14)*128 + rl] = v3.z; xt[(jb+15)*128 + rl] = v3.w;
        __syncthreads();
        #pragma unroll
        for (int jp = 0; jp < 32; ++jp) {
            float w = wt[(jc * 32 + jp) * 32 + kk];
            const float* xr = &xt[jp * 128 + rg * 16];
            float4 x0 = *(const float4*)(xr + 0);
            float4 x1 = *(const float4*)(xr + 4);
            float4 x2 = *(const float4*)(xr + 8);
            float4 x3 = *(const float4*)(xr + 12);
            acc[ 0] += x0.x*w; acc[ 1] += x0.y*w; acc[ 2] += x0.z*w; acc[ 3] += x0.w*w;
            acc[ 4] += x1.x*w; acc[ 5] += x1.y*w; acc[ 6] += x1.z*w; acc[ 7] += x1.w*w;
            acc[ 8] += x2.x*w; acc[ 9] += x2.y*w; acc[10] += x2.z*w; acc[11] += x2.w*w;
            acc[12] += x3.x*w; acc[13] += x3.y*w; acc[14] += x3.z*w; acc[15] += x3.w*w;
        }
    }
    float bb = bclf[kk];
    #pragma unroll
    for (int i = 0; i < 16; ++i)
        logits[(size_t)(r0 + rg * 16 + i) * NK + kk] = acc[i] + bb;
}

// ---------------------------------------------------------------------------
// Viterbi: one wave per batch, ref-exact rounding order
// ---------------------------------------------------------------------------
__global__ __launch_bounds__(64)
void k_viterbi(const float* __restrict__ logits, const int* __restrict__ lengths,
               const float* __restrict__ st, const float* __restrict__ et,
               const float* __restrict__ trans, float* __restrict__ preds) {
    int b = blockIdx.x, lane = threadIdx.x;
    __shared__ unsigned char hist[NT - 1][NK];
    int len = lengths[b];
    int k = lane & 31;
    float wt[32];
    #pragma unroll
    for (int j = 0; j < 32; ++j) wt[j] = trans[j * NK + k];
    const float* lg = logits + (size_t)b * NT * NK;
    float score = st[k] + lg[k];
    for (int t = 1; t < NT; ++t) {
        float emis = lg[t * NK + k];
        float best = -3.4e38f; int bidx = 0;
        #pragma unroll
        for (int j = 0; j < 32; ++j) {
            float cand = (__shfl(score, j, 64) + wt[j]) + emis;
            if (cand > best) { best = cand; bidx = j; }
        }
        bool m = t < len;
        if (lane < 32) hist[t - 1][k] = (unsigned char)(m ? bidx : k);
        score = m ? best : score;
    }
    score += et[k];
    float bv = -3.4e38f; int btag = 0;
    #pragma unroll
    for (int j = 0; j < 32; ++j) {
        float v = __shfl(score, j, 64);
        if (v > bv) { bv = v; btag = j; }
    }
    __syncthreads();
    if (lane == 0) {
        int tag = btag;
        for (int t = NT - 1; t >= 1; --t) {
            preds[(size_t)b * NT + t] = (t < len) ? (float)tag : 0.f;
            tag = hist[t - 1][tag];
        }
        preds[(size_t)b * NT] = (float)tag;
    }
}

// ---------------------------------------------------------------------------
extern "C" void kernel_launch(void* const* d_in, const int* in_sizes, int n_in,
                              void* d_out, int out_size, void* d_ws, size_t ws_size,
                              hipStream_t stream) {
    (void)in_sizes; (void)n_in; (void)out_size;
    const float* x       = (const float*)d_in[0];
    const int*   lengths = (const int*)d_in[1];
    const float* Wih_f = (const float*)d_in[3];
    const float* Whh_f = (const float*)d_in[4];
    const float* b_f   = (const float*)d_in[5];
    const float* Wih_b = (const float*)d_in[6];
    const float* Whh_b = (const float*)d_in[7];
    const float* b_b   = (const float*)d_in[8];
    const float* W_clf = (const float*)d_in[9];
    const float* b_clf = (const float*)d_in[10];
    const float* st    = (const float*)d_in[11];
    const float* et    = (const float*)d_in[12];
    const float* trans = (const float*)d_in[13];

    float* logits = (float*)d_out;
    float* preds  = logits + (size_t)NBT * NK;

    // scratch inside the (not-yet-written) logits region of d_out (4 MB):
    // ww 2 MB @0; flags 1 MB @2MB. k_clf overwrites both later.
    float* wwp = logits;
    int*   flg = (int*)(logits + 524288);
    const size_t FLB = (size_t)262144 * 4;            // 2*64*4*512 ints

    const size_t XPB = (size_t)NBT * NG * 4;          // 134,217,728
    bool conc = ws_size >= 2 * XPB;

    char* ws = (char*)d_ws;
    float* xp0 = (float*)ws;
    float* xp1 = conc ? (float*)(ws + XPB) : xp0;
    float *hsF, *hsB; int hstr;
    if (conc) {
        hsF = xp0; hsB = xp1; hstr = NG;              // h aliases gate-i columns
    } else {
        hsF = (float*)(ws + XPB); hsB = hsF + (size_t)NB * NT * NH; hstr = NH;
    }

    hipMemsetAsync(flg, 0, FLB, stream);
    k_wprep3<<<2048, 256, 0, stream>>>(Whh_f, Whh_b, wwp);

    if (conc) {
        k_gemmM<<<dim3(16, 256), 512, 0, stream>>>(x, Wih_f, Wih_b, b_f, b_b,
                                                   xp0, xp1, 0);
        k_lstm4b<<<256, 512, 0, stream>>>(xp0, xp1, wwp, lengths,
                                          hsF, hsB, hstr, flg, 0);
    } else {
        k_gemmM<<<dim3(8, 256), 512, 0, stream>>>(x, Wih_f, Wih_b, b_f, b_b,
                                                  xp0, xp0, 0);
        k_lstm4b<<<128, 512, 0, stream>>>(xp0, xp0, wwp, lengths,
                                          hsF, hsB, hstr, flg, 0);
        k_gemmM<<<dim3(8, 256), 512, 0, stream>>>(x, Wih_f, Wih_b, b_f, b_b,
                                                  xp0, xp0, 8);
        k_lstm4b<<<128, 512, 0, stream>>>(xp0, xp0, wwp, lengths,
                                          hsF, hsB, hstr, flg, 32);
    }
    k_clf<<<256, 256, 0, stream>>>(hsF, hsB, hstr, W_clf, b_clf, logits);
    k_viterbi<<<NB, 64, 0, stream>>>(logits, lengths, st, et, trans, preds);
}

// Round 19
// 2140.689 us; speedup vs baseline: 1.3084x; 1.0163x over previous
//
#include <hip/hip_runtime.h>
#include <math.h>

#define NB 64
#define NT 512
#define ND 512
#define NH 256
#define NG 1024   // 4*H
#define NK 32
#define NBT (NB*NT)

typedef __attribute__((ext_vector_type(8))) short short8;
typedef __attribute__((ext_vector_type(4))) float f32x4;

__device__ __forceinline__ float sigf(float x) { return 1.f / (1.f + expf(-x)); }
__device__ __forceinline__ float hsum4(float4 v) { return v.x + v.y + v.z + v.w; }

__device__ __forceinline__ unsigned short f2bf(float f) {
    unsigned u = __float_as_uint(f);
    unsigned r = u + 0x7FFF + ((u >> 16) & 1);   // RNE to bf16
    return (unsigned short)(r >> 16);
}
__device__ __forceinline__ float bf2f(unsigned short s) {
    return __uint_as_float((unsigned)s << 16);
}

// ---------------------------------------------------------------------------
// Weight prep (round-8 layout, unchanged):
// ww[(((dir*4+s)*32 + g*8+j)*512 + tid)*4 + e] = Whh_dir[g*256+s*64+u][part*32+j*4+e]
// ---------------------------------------------------------------------------
__global__ void k_wprep3(const float* __restrict__ Wf, const float* __restrict__ Wb,
                         float* __restrict__ ww) {
    int f = blockIdx.x * 256 + threadIdx.x;      // 0 .. 524287
    int e   = f & 3;
    int tid = (f >> 2) & 511;
    int gj  = (f >> 11) & 31;
    int s   = (f >> 16) & 3;
    int dir = (f >> 18) & 1;
    int u = tid & 63, part = tid >> 6;
    int g = gj >> 3, j = gj & 7;
    const float* W = dir ? Wb : Wf;
    int row = g * 256 + s * 64 + u;
    int col = part * 32 + j * 4 + e;
    ww[f] = W[row * 256 + col];
}

// ---------------------------------------------------------------------------
// Input projection GEMM via MFMA, split-bf16 3-term — round-17 VERBATIM.
// ---------------------------------------------------------------------------
__global__ void
__attribute__((amdgpu_flat_work_group_size(512, 512)))
k_gemmM(const float* __restrict__ x, const float* __restrict__ Wf,
        const float* __restrict__ Wb, const float* __restrict__ bf,
        const float* __restrict__ bb, float* __restrict__ xpF,
        float* __restrict__ xpB, int bxBase) {
    __shared__ unsigned short Ahi[128 * 40], Alo[128 * 40];
    __shared__ unsigned short Bhi[128 * 40], Blo[128 * 40];
    int tid = threadIdx.x;
    int bx = blockIdx.x + bxBase;
    int dir = bx >> 3;
    const float* W    = dir ? Wb : Wf;
    const float* bias = dir ? bb : bf;
    float* xp         = dir ? xpB : xpF;
    size_t r0 = (size_t)blockIdx.y << 7;
    int c0 = (bx & 7) << 7;

    int srow = tid >> 2, sk = (tid & 3) << 3;    // staging row, k-offset
    const float* xs = x + (r0 + srow) * ND + sk;
    const float* wsr = W + (size_t)(c0 + srow) * ND + sk;
    int sb = srow * 40 + sk;                     // LDS base (bf16 units)

    int lane = tid & 63;
    int wv = tid >> 6;                           // 8 waves
    int wm = wv & 3;                             // m-quad (rows wm*32)
    int wn = wv >> 2;                            // n-half (cols wn*64)
    int frow = lane & 15;
    int fk = (lane >> 4) << 3;

    f32x4 acc[2][4];
    #pragma unroll
    for (int i = 0; i < 2; ++i)
        #pragma unroll
        for (int j = 0; j < 4; ++j)
            acc[i][j] = (f32x4){0.f, 0.f, 0.f, 0.f};

    for (int kt = 0; kt < ND; kt += 32) {
        float4 v0 = *(const float4*)(xs + kt);
        float4 v1 = *(const float4*)(xs + kt + 4);
        float4 w0 = *(const float4*)(wsr + kt);
        float4 w1 = *(const float4*)(wsr + kt + 4);
        float xv[8]  = {v0.x, v0.y, v0.z, v0.w, v1.x, v1.y, v1.z, v1.w};
        float wvv[8] = {w0.x, w0.y, w0.z, w0.w, w1.x, w1.y, w1.z, w1.w};
        short8 xh, xl, wh, wl;
        #pragma unroll
        for (int e = 0; e < 8; ++e) {
            unsigned short h = f2bf(xv[e]);
            xh[e] = (short)h;
            xl[e] = (short)f2bf(xv[e] - bf2f(h));
            unsigned short g = f2bf(wvv[e]);
            wh[e] = (short)g;
            wl[e] = (short)f2bf(wvv[e] - bf2f(g));
        }
        __syncthreads();
        *(short8*)&Ahi[sb] = xh;  *(short8*)&Alo[sb] = xl;
        *(short8*)&Bhi[sb] = wh;  *(short8*)&Blo[sb] = wl;
        __syncthreads();

        short8 ah[2], al[2], bh[4], bl[4];
        #pragma unroll
        for (int mi = 0; mi < 2; ++mi) {
            int ar = (wm * 32 + mi * 16 + frow) * 40 + fk;
            ah[mi] = *(const short8*)&Ahi[ar];
            al[mi] = *(const short8*)&Alo[ar];
        }
        #pragma unroll
        for (int ni = 0; ni < 4; ++ni) {
            int br = (wn * 64 + ni * 16 + frow) * 40 + fk;
            bh[ni] = *(const short8*)&Bhi[br];
            bl[ni] = *(const short8*)&Blo[br];
        }
        #pragma unroll
        for (int mi = 0; mi < 2; ++mi)
            #pragma unroll
            for (int ni = 0; ni < 4; ++ni) {
                acc[mi][ni] = __builtin_amdgcn_mfma_f32_16x16x32_bf16(
                    ah[mi], bh[ni], acc[mi][ni], 0, 0, 0);
                acc[mi][ni] = __builtin_amdgcn_mfma_f32_16x16x32_bf16(
                    ah[mi], bl[ni], acc[mi][ni], 0, 0, 0);
                acc[mi][ni] = __builtin_amdgcn_mfma_f32_16x16x32_bf16(
                    al[mi], bh[ni], acc[mi][ni], 0, 0, 0);
            }
    }

    #pragma unroll
    for (int mi = 0; mi < 2; ++mi)
        #pragma unroll
        for (int ni = 0; ni < 4; ++ni) {
            int orow = wm * 32 + mi * 16 + ((lane >> 4) << 2);
            int ocol = c0 + wn * 64 + ni * 16 + frow;
            float bb2 = bias[ocol];
            float* ob = xp + (r0 + orow) * NG + ocol;
            #pragma unroll
            for (int r = 0; r < 4; ++r)
                ob[(size_t)r * NG] = acc[mi][ni][r] + bb2;
        }
}

// ---------------------------------------------------------------------------
// lstm macros — 24 named VGPR quads (j=0..5 per gate) + 8 LDS quads (j=6,7).
// Same j-ascending accumulation order: bit-identical h.
// ---------------------------------------------------------------------------
#define FMA4(A, W, H) { (A).x += (W).x*(H).x; (A).y += (W).y*(H).y; \
                        (A).z += (W).z*(H).z; (A).w += (W).w*(H).w; }

#define DECLR(g) \
    float4 wr##g##_0 = wwp[qb + ((g)*8+0)*512]; \
    float4 wr##g##_1 = wwp[qb + ((g)*8+1)*512]; \
    float4 wr##g##_2 = wwp[qb + ((g)*8+2)*512]; \
    float4 wr##g##_3 = wwp[qb + ((g)*8+3)*512]; \
    float4 wr##g##_4 = wwp[qb + ((g)*8+4)*512]; \
    float4 wr##g##_5 = wwp[qb + ((g)*8+5)*512];

#define DOTRJ(j) { float4 h_ = *(const float4*)(hb + (j)*4); \
    FMA4(a0, wr0_##j, h_) FMA4(a1, wr1_##j, h_) \
    FMA4(a2, wr2_##j, h_) FMA4(a3, wr3_##j, h_) }

#define DOTLJ(jj, j) { float4 h_ = *(const float4*)(hb + (j)*4); \
    { float4 l_ = lds_w[(0*2+(jj))*512 + tid]; FMA4(a0, l_, h_) } \
    { float4 l_ = lds_w[(1*2+(jj))*512 + tid]; FMA4(a1, l_, h_) } \
    { float4 l_ = lds_w[(2*2+(jj))*512 + tid]; FMA4(a2, l_, h_) } \
    { float4 l_ = lds_w[(3*2+(jj))*512 + tid]; FMA4(a3, l_, h_) } }

#define DOTALL DOTRJ(0) DOTRJ(1) DOTRJ(2) DOTRJ(3) DOTRJ(4) DOTRJ(5) \
               DOTLJ(0,6) DOTLJ(1,7)

// ---------------------------------------------------------------------------
// LSTM recurrence — round-18 skeleton with barrier I REMOVED:
// each update wave (wv 0/1) publishes its batch's h, does a WAVE-LOCAL
// vmcnt drain, and releases its own batch's flag (r10-validated mechanism).
// 3 barriers/step (C, E, G). hfull/lds_part reuse ordered by C/E of the
// next step. Accumulation order unchanged -> bit-identical h.
// ---------------------------------------------------------------------------
__global__ void
__attribute__((amdgpu_flat_work_group_size(512, 512)))
k_lstm4c(const float* __restrict__ xpF, const float* __restrict__ xpB,
         const float* __restrict__ ww, const int* __restrict__ lengths,
         float* hsF, float* hsB, int hstr, int* flags, int gBase) {
    int bi = blockIdx.x;
    int g   = (bi & 7) + 8 * (bi >> 5) + gBase;  // 0..63: dir*32 + group
    int s   = (bi >> 3) & 3;                     // u-slice; siblings share bi&7
    int dir = g >> 5;
    int b0  = (g & 31) * 2;
    const float* xp = dir ? xpB : xpF;
    float* hsD      = dir ? hsB : hsF;

    int tid = threadIdx.x;
    int u  = tid & 63;
    int wv = tid >> 6;                           // wave = v-chunk (part) 0..7

    __shared__ float4 lds_w[8 * 512];            // 64 KB
    __shared__ __align__(16) float hfull[2][256];
    __shared__ float4 lds_part[2][8][64];        // 16 KB
    __shared__ int len4[2];

    const float4* wwp = (const float4*)ww;
    int qb = ((dir * 4 + s) * 32) * 512 + tid;

    DECLR(0) DECLR(1) DECLR(2) DECLR(3)          // 24 named quads -> VGPRs
    #pragma unroll
    for (int gg = 0; gg < 4; ++gg)
        #pragma unroll
        for (int jj = 0; jj < 2; ++jj)
            lds_w[(gg * 2 + jj) * 512 + tid] = wwp[qb + (gg * 8 + 6 + jj) * 512];

    if (tid < 2) len4[tid] = lengths[b0 + tid];
    ((float*)hfull)[tid] = 0.f;                  // 512 floats exactly
    float c_state = 0.f;
    __syncthreads();

    // staging assignment (threads 0..191): 96 ulongs per batch
    int sb   = (tid < 192) ? (tid / 96) : 0;     // batch 0..1
    int sr   = tid - sb * 96;
    int spsi = (sr >> 5) & 3, sq = sr & 31;
    int ssl  = spsi + (spsi >= s);               // partner slice
    unsigned long long* sdst =
        (unsigned long long*)&hfull[sb & 1][ssl * 64 + sq * 2];
    const float* ssrc0 = hsD + (size_t)(b0 + (sb & 1)) * NT * hstr + ssl * 64 + sq * 2;

    // poller assignment (threads 0..7): (pb, ps)
    int pb = tid & 1, ps = (tid >> 1) & 3;
    const int* pollp = flags + ((((dir << 6) + b0 + pb) << 2) + ps) * 512;

    // update-wave pointers (waves 0..1): own h row + own batch flag
    float* hwp = hsD + (size_t)(b0 + (wv & 1)) * NT * hstr + (s << 6) + u;
    int* flrel = flags + ((((dir << 6) + b0 + (wv & 1)) << 2) + s) * 512;

    for (int tt = 0; tt < NT; ++tt) {
        int t = dir ? (NT - 1 - tt) : tt;

        // A: xp prefetch (waves 0..1, batch wv's 4 gate columns)
        float x0 = 0.f, x1 = 0.f, x2 = 0.f, x3 = 0.f;
        if (wv < 2) {
            const float* xr = xp + ((size_t)(b0 + wv) * NT + t) * NG + (s << 6) + u;
            x0 = xr[0]; x1 = xr[256]; x2 = xr[512]; x3 = xr[768];
        }
        // B: poll partner flags RELAXED
        if (tt > 0 && tid < 8 && ps != s && t < len4[pb]) {
            const int* fp = pollp + (tt - 1);
            while (__hip_atomic_load(fp, __ATOMIC_RELAXED,
                                     __HIP_MEMORY_SCOPE_AGENT) == 0) {}
        }
        __syncthreads();   // C: flags observed; prev-step hfull/lds_part safe

        // D: stage partner h via 64-bit relaxed atomic loads
        if (tt > 0 && tid < 192 && t < len4[sb]) {
            int t_prev = dir ? (t + 1) : (t - 1);
            unsigned long long v = __hip_atomic_load(
                (const unsigned long long*)(ssrc0 + (size_t)t_prev * hstr),
                __ATOMIC_RELAXED, __HIP_MEMORY_SCOPE_AGENT);
            *sdst = v;
        }
        __syncthreads();   // E

        // F: 2 dots (block-uniform skip per batch)
        #pragma unroll
        for (int b = 0; b < 2; ++b) {
            if (tt > 0 && t < len4[b]) {
                const float* hb = &hfull[b][wv << 5];
                float4 a0 = {0.f,0.f,0.f,0.f}, a1 = a0, a2 = a0, a3 = a0;
                DOTALL
                lds_part[b][wv][u] = make_float4(hsum4(a0), hsum4(a1),
                                                 hsum4(a2), hsum4(a3));
            }
        }
        __syncthreads();   // G

        // H: update (wave b owns batch b); publish h, wave-local drain,
        //    per-wave flag release (no block barrier needed).
        if (wv < 2) {
            bool act = t < len4[wv];
            float pi, pf, pg, po;
            if (tt > 0 && act) {
                float4 q0 = lds_part[wv][0][u], q1 = lds_part[wv][1][u];
                float4 q2 = lds_part[wv][2][u], q3 = lds_part[wv][3][u];
                float4 q4 = lds_part[wv][4][u], q5 = lds_part[wv][5][u];
                float4 q6 = lds_part[wv][6][u], q7 = lds_part[wv][7][u];
                pi = q0.x+q1.x+q2.x+q3.x+q4.x+q5.x+q6.x+q7.x + x0;
                pf = q0.y+q1.y+q2.y+q3.y+q4.y+q5.y+q6.y+q7.y + x1;
                pg = q0.z+q1.z+q2.z+q3.z+q4.z+q5.z+q6.z+q7.z + x2;
                po = q0.w+q1.w+q2.w+q3.w+q4.w+q5.w+q6.w+q7.w + x3;
            } else {
                pi = x0; pf = x1; pg = x2; po = x3;
            }
            float h_old = hfull[wv][(s << 6) + u];
            float hv = h_old;
            if (act) {
                float gi = sigf(pi), gf = sigf(pf), gg = tanhf(pg), go = sigf(po);
                c_state = gf * c_state + gi * gg;
                hv = go * tanhf(c_state);
            }
            __hip_atomic_store(hwp + (size_t)t * hstr, hv,
                               __ATOMIC_RELAXED, __HIP_MEMORY_SCOPE_AGENT);
            asm volatile("s_waitcnt vmcnt(0)" ::: "memory");  // wave-local drain
            if (u == 0)
                __hip_atomic_store(flrel + tt, 1, __ATOMIC_RELAXED,
                                   __HIP_MEMORY_SCOPE_AGENT);
            hfull[wv][(s << 6) + u] = hv;        // visible at next step's C
        }
        // (barrier I removed)
    }
}

// ---------------------------------------------------------------------------
// Classifier GEMM
// ---------------------------------------------------------------------------
__global__ __launch_bounds__(256, 4)
void k_clf(const float* __restrict__ hsF, const float* __restrict__ hsB,
           int hstr, const float* __restrict__ Wclf, const float* __restrict__ bclf,
           float* __restrict__ logits) {
    __shared__ float wt[512 * 32];
    __shared__ float xt[32 * 128];
    int tid = threadIdx.x;
    int r0 = blockIdx.x << 7;
    #pragma unroll
    for (int e = 0; e < 64; ++e) {
        int idx = e * 256 + tid;
        int kk = idx >> 9, j = idx & 511;
        wt[j * 32 + kk] = Wclf[idx];
    }
    int rl = tid >> 1, half = tid & 1;
    int kk = tid & 31, rg = tid >> 5;
    float acc[16] = {};
    for (int jc = 0; jc < 16; ++jc) {
        const float* src = (jc < 8 ? hsF : hsB) +
                           (size_t)(r0 + rl) * hstr + ((jc & 7) << 5) + (half << 4);
        float4 v0 = *(const float4*)(src + 0);
        float4 v1 = *(const float4*)(src + 4);
        float4 v2 = *(const float4*)(src + 8);
        float4 v3 = *(const float4*)(src + 12);
        __syncthreads();
        int jb = half << 4;
        xt[(jb+ 0)*128 + rl] = v0.x; xt[(jb+ 1)*128 + rl] = v0.y;
        xt[(jb+ 2)*128 + rl] = v0.z; xt[(jb+ 3)*128 + rl] = v0.w;
        xt[(jb+ 4)*128 + rl] = v1.x; xt[(jb+ 5)*128 + rl] = v1.y;
        xt[(jb+ 6)*128 + rl] = v1.z; xt[(jb+ 7)*128 + rl] = v1.w;
        xt[(jb+ 8)*128 + rl] = v2.x; xt[(jb+ 9)*128 + rl] = v2.y;
        xt[(jb+10)*128 + rl] = v2.z; xt[(jb+11)*128 + rl] = v2.w;
        xt[(jb+12)*128 + rl] = v3.x; xt[(jb+13)*128 + rl] = v3.y;
        xt[(jb+14)*128 + rl] = v3.z; xt[(jb+15)*128 + rl] = v3.w;
        __syncthreads();
        #pragma unroll
        for (int jp = 0; jp < 32; ++jp) {
            float w = wt[(jc * 32 + jp) * 32 + kk];
            const float* xr = &xt[jp * 128 + rg * 16];
            float4 x0 = *(const float4*)(xr + 0);
            float4 x1 = *(const float4*)(xr + 4);
            float4 x2 = *(const float4*)(xr + 8);
            float4 x3 = *(const float4*)(xr + 12);
            acc[ 0] += x0.x*w; acc[ 1] += x0.y*w; acc[ 2] += x0.z*w; acc[ 3] += x0.w*w;
            acc[ 4] += x1.x*w; acc[ 5] += x1.y*w; acc[ 6] += x1.z*w; acc[ 7] += x1.w*w;
            acc[ 8] += x2.x*w; acc[ 9] += x2.y*w; acc[10] += x2.z*w; acc[11] += x2.w*w;
            acc[12] += x3.x*w; acc[13] += x3.y*w; acc[14] += x3.z*w; acc[15] += x3.w*w;
        }
    }
    float bb = bclf[kk];
    #pragma unroll
    for (int i = 0; i < 16; ++i)
        logits[(size_t)(r0 + rg * 16 + i) * NK + kk] = acc[i] + bb;
}

// ---------------------------------------------------------------------------
// Viterbi: one wave per batch, ref-exact rounding order
// ---------------------------------------------------------------------------
__global__ __launch_bounds__(64)
void k_viterbi(const float* __restrict__ logits, const int* __restrict__ lengths,
               const float* __restrict__ st, const float* __restrict__ et,
               const float* __restrict__ trans, float* __restrict__ preds) {
    int b = blockIdx.x, lane = threadIdx.x;
    __shared__ unsigned char hist[NT - 1][NK];
    int len = lengths[b];
    int k = lane & 31;
    float wt[32];
    #pragma unroll
    for (int j = 0; j < 32; ++j) wt[j] = trans[j * NK + k];
    const float* lg = logits + (size_t)b * NT * NK;
    float score = st[k] + lg[k];
    for (int t = 1; t < NT; ++t) {
        float emis = lg[t * NK + k];
        float best = -3.4e38f; int bidx = 0;
        #pragma unroll
        for (int j = 0; j < 32; ++j) {
            float cand = (__shfl(score, j, 64) + wt[j]) + emis;
            if (cand > best) { best = cand; bidx = j; }
        }
        bool m = t < len;
        if (lane < 32) hist[t - 1][k] = (unsigned char)(m ? bidx : k);
        score = m ? best : score;
    }
    score += et[k];
    float bv = -3.4e38f; int btag = 0;
    #pragma unroll
    for (int j = 0; j < 32; ++j) {
        float v = __shfl(score, j, 64);
        if (v > bv) { bv = v; btag = j; }
    }
    __syncthreads();
    if (lane == 0) {
        int tag = btag;
        for (int t = NT - 1; t >= 1; --t) {
            preds[(size_t)b * NT + t] = (t < len) ? (float)tag : 0.f;
            tag = hist[t - 1][tag];
        }
        preds[(size_t)b * NT] = (float)tag;
    }
}

// ---------------------------------------------------------------------------
extern "C" void kernel_launch(void* const* d_in, const int* in_sizes, int n_in,
                              void* d_out, int out_size, void* d_ws, size_t ws_size,
                              hipStream_t stream) {
    (void)in_sizes; (void)n_in; (void)out_size;
    const float* x       = (const float*)d_in[0];
    const int*   lengths = (const int*)d_in[1];
    const float* Wih_f = (const float*)d_in[3];
    const float* Whh_f = (const float*)d_in[4];
    const float* b_f   = (const float*)d_in[5];
    const float* Wih_b = (const float*)d_in[6];
    const float* Whh_b = (const float*)d_in[7];
    const float* b_b   = (const float*)d_in[8];
    const float* W_clf = (const float*)d_in[9];
    const float* b_clf = (const float*)d_in[10];
    const float* st    = (const float*)d_in[11];
    const float* et    = (const float*)d_in[12];
    const float* trans = (const float*)d_in[13];

    float* logits = (float*)d_out;
    float* preds  = logits + (size_t)NBT * NK;

    // scratch inside the (not-yet-written) logits region of d_out (4 MB):
    // ww 2 MB @0; flags 1 MB @2MB. k_clf overwrites both later.
    float* wwp = logits;
    int*   flg = (int*)(logits + 524288);
    const size_t FLB = (size_t)262144 * 4;            // 2*64*4*512 ints

    const size_t XPB = (size_t)NBT * NG * 4;          // 134,217,728
    bool conc = ws_size >= 2 * XPB;

    char* ws = (char*)d_ws;
    float* xp0 = (float*)ws;
    float* xp1 = conc ? (float*)(ws + XPB) : xp0;
    float *hsF, *hsB; int hstr;
    if (conc) {
        hsF = xp0; hsB = xp1; hstr = NG;              // h aliases gate-i columns
    } else {
        hsF = (float*)(ws + XPB); hsB = hsF + (size_t)NB * NT * NH; hstr = NH;
    }

    hipMemsetAsync(flg, 0, FLB, stream);
    k_wprep3<<<2048, 256, 0, stream>>>(Whh_f, Whh_b, wwp);

    if (conc) {
        k_gemmM<<<dim3(16, 256), 512, 0, stream>>>(x, Wih_f, Wih_b, b_f, b_b,
                                                   xp0, xp1, 0);
        k_lstm4c<<<256, 512, 0, stream>>>(xp0, xp1, wwp, lengths,
                                          hsF, hsB, hstr, flg, 0);
    } else {
        k_gemmM<<<dim3(8, 256), 512, 0, stream>>>(x, Wih_f, Wih_b, b_f, b_b,
                                                  xp0, xp0, 0);
        k_lstm4c<<<128, 512, 0, stream>>>(xp0, xp0, wwp, lengths,
                                          hsF, hsB, hstr, flg, 0);
        k_gemmM<<<dim3(8, 256), 512, 0, stream>>>(x, Wih_f, Wih_b, b_f, b_b,
                                                  xp0, xp0, 8);
        k_lstm4c<<<128, 512, 0, stream>>>(xp0, xp0, wwp, lengths,
                                          hsF, hsB, hstr, flg, 32);
    }
    k_clf<<<256, 256, 0, stream>>>(hsF, hsB, hstr, W_clf, b_clf, logits);
    k_viterbi<<<NB, 64, 0, stream>>>(logits, lengths, st, et, trans, preds);
}